// Round 4
// baseline (556.181 us; speedup 1.0000x reference)
//
#include <hip/hip_runtime.h>

#define N_NODES 50000
#define N_EDGES 100000
#define DD 32
#define STEPS 5
#define ETYPES 8
#define CAP_T 13312              // per-type slot capacity (mult of 64; mean 12500, sigma~105)
#define CAP (ETYPES * CAP_T)     // 106496 sorted slots
#define TRASH N_EDGES            // trash row index in fea arrays (extra row allocated)
#define SCAN_B 49                // 49 blocks * 1024 = 50176 >= N_NODES

#define NPT 2            // nodes per thread (gru)
#define NPB 64           // nodes per block (gru)
#define CAT_STRIDE 100   // floats per cat row (96 + 4 pad)

// prop[n,j] = emb[token[n],j]; zero cnt_in/cnt_out/tcnt; dummy-init sorted slots.
__global__ void init_kernel(const int* __restrict__ token,
                            const float* __restrict__ emb,
                            float* __restrict__ prop,
                            int* __restrict__ cnt,      // 2N+8: cnt_in | cnt_out | tcnt
                            int* __restrict__ se,
                            int* __restrict__ spi,
                            int* __restrict__ spo) {
    int idx = blockIdx.x * 256 + threadIdx.x;   // over N*D = 1.6M, exact grid
    int n = idx >> 5, j = idx & 31;
    prop[idx] = emb[token[n] * DD + j];
    if (idx < 2 * N_NODES + ETYPES) cnt[idx] = 0;
    if (idx < CAP) { se[idx] = 0; spi[idx] = TRASH; spo[idx] = TRASH; }
}

// One pass over edges: per-node ranks (global atomics) + type-bucket slot via
// block-local LDS histogram (one global atomic per type per block for the base).
__global__ void hist_kernel(const int* __restrict__ etype,
                            const int* __restrict__ src,
                            const int* __restrict__ dst,
                            int* __restrict__ cnt_in, int* __restrict__ cnt_out,
                            int* __restrict__ tcnt,
                            int* __restrict__ rank_in, int* __restrict__ rank_out,
                            int* __restrict__ qe) {
    __shared__ int lh[ETYPES], lbase[ETYPES];
    int tid = threadIdx.x;
    int e = blockIdx.x * 256 + tid;
    if (tid < ETYPES) lh[tid] = 0;
    __syncthreads();
    int t = 0, lr = 0;
    bool v = e < N_EDGES;
    if (v) {
        t = etype[e];
        lr = atomicAdd(&lh[t], 1);
        rank_in[e]  = atomicAdd(&cnt_in[dst[e]], 1);
        rank_out[e] = atomicAdd(&cnt_out[src[e]], 1);
    }
    __syncthreads();
    if (tid < ETYPES) lbase[tid] = atomicAdd(&tcnt[tid], lh[tid]);
    __syncthreads();
    if (v) qe[e] = t * CAP_T + lbase[t] + lr;
}

// Hierarchical scan stage 1: block-local exclusive scan (coalesced, wide).
__global__ __launch_bounds__(1024) void
scan1(const int* __restrict__ cnt_in, const int* __restrict__ cnt_out,
      int* __restrict__ off_in, int* __restrict__ off_out,
      int* __restrict__ bsum) {
    __shared__ int s[1024];
    int b = blockIdx.x;
    int ab = (b < SCAN_B) ? b : b - SCAN_B;
    const int* a = (b < SCAN_B) ? cnt_in : cnt_out;
    int* o = (b < SCAN_B) ? off_in : off_out;
    int i = ab * 1024 + threadIdx.x;
    int x = (i < N_NODES) ? a[i] : 0;
    s[threadIdx.x] = x;
    __syncthreads();
    for (int ofs = 1; ofs < 1024; ofs <<= 1) {
        int u = (threadIdx.x >= ofs) ? s[threadIdx.x - ofs] : 0;
        __syncthreads();
        s[threadIdx.x] += u;
        __syncthreads();
    }
    if (i < N_NODES) o[i] = s[threadIdx.x] - x;   // local exclusive
    if (threadIdx.x == 1023) bsum[b] = s[1023];
}

// Stage 2: scan 98 block sums. Since sum(cnt_in)=sum(cnt_out)=E exactly, one
// combined scan with a constant -E correction splits the two arrays.
__global__ void scan2(const int* __restrict__ bsum, int* __restrict__ ebase,
                      int* __restrict__ off_in, int* __restrict__ off_out) {
    __shared__ int s[128];
    int t = threadIdx.x;
    int x = (t < 2 * SCAN_B) ? bsum[t] : 0;
    s[t] = x;
    __syncthreads();
    for (int ofs = 1; ofs < 128; ofs <<= 1) {
        int u = (t >= ofs) ? s[t - ofs] : 0;
        __syncthreads();
        s[t] += u;
        __syncthreads();
    }
    if (t < SCAN_B) ebase[t] = s[t] - x;
    else if (t < 2 * SCAN_B) ebase[t] = s[t] - x - N_EDGES;
    if (t == 0) { off_in[N_NODES] = N_EDGES; off_out[N_NODES] = N_EDGES; }
}

// Stage 3: add scanned block bases.
__global__ __launch_bounds__(1024) void
scan3(int* __restrict__ off_in, int* __restrict__ off_out,
      const int* __restrict__ ebase) {
    int b = blockIdx.x;
    int ab = (b < SCAN_B) ? b : b - SCAN_B;
    int* o = (b < SCAN_B) ? off_in : off_out;
    int i = ab * 1024 + threadIdx.x;
    if (i < N_NODES) o[i] += ebase[b];
}

// Scatter edge records into type-sorted slots with final CSR positions; also
// record the owning node of every CSR row for the gru flat-stream gather.
__global__ void place_kernel(const int* __restrict__ src,
                             const int* __restrict__ dst,
                             const int* __restrict__ in_off,
                             const int* __restrict__ out_off,
                             const int* __restrict__ rank_in,
                             const int* __restrict__ rank_out,
                             const int* __restrict__ qe,
                             int* __restrict__ se, int* __restrict__ spi,
                             int* __restrict__ spo,
                             int* __restrict__ node_in,
                             int* __restrict__ node_out) {
    int e = blockIdx.x * 256 + threadIdx.x;
    if (e < N_EDGES) {
        int q = qe[e];
        int pi = in_off[dst[e]]  + rank_in[e];
        int po = out_off[src[e]] + rank_out[e];
        node_in[pi]  = dst[e];
        node_out[po] = src[e];
        if (q < CAP) {                          // guard: never OOB even on 8-sigma
            se[q]  = src[e];
            spi[q] = pi;
            spo[q] = po;
        }
    }
}

// Wave = 16 same-type edges (two half-waves of 8). W column j lives in 64 VGPRs
// per lane for the whole wave: zero weight memory traffic in the inner loop.
__global__ __launch_bounds__(256) void
edge_kernel(const int* __restrict__ se, const int* __restrict__ spi,
            const int* __restrict__ spo, const float* __restrict__ W_edge,
            const float* __restrict__ prop,
            float* __restrict__ fea_in, float* __restrict__ fea_out) {
    int wid = blockIdx.x * 4 + (threadIdx.x >> 6);
    int lane = threadIdx.x & 63;
    int j = lane & 31;
    int slot0 = wid * 16 + ((lane >> 5) << 3);     // this half-wave's 8 slots
    int type = (wid * 16) / CAP_T;                 // wave-uniform (CAP_T % 16 == 0)
    const float2* Wt = (const float2*)W_edge + (size_t)type * (DD * DD);
    float2 w[DD];
#pragma unroll
    for (int i = 0; i < DD; ++i) w[i] = Wt[i * DD + j];   // 8KB once per wave
    int s[8], pi[8], po[8];
    float h[8];
#pragma unroll
    for (int k = 0; k < 8; ++k) {
        s[k] = se[slot0 + k]; pi[k] = spi[slot0 + k]; po[k] = spo[slot0 + k];
    }
#pragma unroll
    for (int k = 0; k < 8; ++k) h[k] = prop[(size_t)s[k] * DD + j];
    float aF[8] = {0.f,0.f,0.f,0.f,0.f,0.f,0.f,0.f};
    float aR[8] = {0.f,0.f,0.f,0.f,0.f,0.f,0.f,0.f};
#pragma unroll
    for (int i = 0; i < DD; ++i) {
#pragma unroll
        for (int k = 0; k < 8; ++k) {
            float hi = __shfl(h[k], i, 32);        // broadcast within half-wave
            aF[k] = fmaf(hi, w[i].x, aF[k]);
            aR[k] = fmaf(hi, w[i].y, aR[k]);
        }
    }
#pragma unroll
    for (int k = 0; k < 8; ++k) {
        fea_in [(size_t)pi[k] * DD + j] = aF[k];   // plain 128B-row stores
        fea_out[(size_t)po[k] * DD + j] = aR[k];
    }
}

__device__ __forceinline__ void fma4(float (&acc)[4], float c, const float4& w) {
    acc[0] = fmaf(c, w.x, acc[0]);
    acc[1] = fmaf(c, w.y, acc[1]);
    acc[2] = fmaf(c, w.z, acc[2]);
    acc[3] = fmaf(c, w.w, acc[3]);
}
__device__ __forceinline__ float sigm(float x) {
    return 1.f / (1.f + __expf(-x));
}
__device__ __forceinline__ float fast_tanh(float x) {
    x = fminf(fmaxf(x, -15.f), 15.f);
    float e = __expf(2.f * x);
    return (e - 1.f) / (e + 1.f);
}

// Block = 256 threads = 64 nodes. Weights (W_r|W_z|W_t = 36.9 KB) staged to LDS
// once per block (kills the 36KB>L1 thrash); in/out segment sums gathered by
// flat-streaming the block's contiguous CSR row range with LDS atomicAdd.
// LDS total 62.5 KB -> 2 blocks/CU.
__global__ __launch_bounds__(256) void
gru_kernel(const float* __restrict__ W_r, const float* __restrict__ b_r,
           const float* __restrict__ W_z, const float* __restrict__ b_z,
           const float* __restrict__ W_t, const float* __restrict__ b_t,
           const float* __restrict__ fea_in,
           const float* __restrict__ fea_out,
           const int* __restrict__ in_off,
           const int* __restrict__ out_off,
           const int* __restrict__ node_in,
           const int* __restrict__ node_out,
           float* __restrict__ prop,
           float* __restrict__ out2) {
    __shared__ float cat[NPB * CAT_STRIDE];           // 25.6 KB
    __shared__ float4 wlds[3 * 96 * 8];               // 36.9 KB: W_r|W_z|W_t
    float4* cat4 = (float4*)cat;                      // row stride 25 float4
    const int tid = threadIdx.x;
    const int n0 = blockIdx.x * NPB;
    const int nhi = min(n0 + NPB, N_NODES);
    const int jq = tid & 7;
    const int ng = tid >> 3;

    // ---- zero in/out slots; stage prop + weights ----
    {
        const float4 zz = {0.f, 0.f, 0.f, 0.f};
#pragma unroll
        for (int q = 0; q < 4; ++q) {                 // NPB*16 = 1024 float4
            int i = q * 256 + tid;
            int node = i >> 4, slot = i & 15;
            cat4[node * 25 + slot] = zz;
        }
        const float4* p4 = (const float4*)(prop + (size_t)n0 * DD);
#pragma unroll
        for (int q = 0; q < 2; ++q) {                 // NPB*8 = 512 float4
            int i = q * 256 + tid;
            int node = i >> 3, c4 = i & 7;
            cat4[node * 25 + 16 + c4] = (n0 + node < nhi) ? p4[i] : zz;
        }
        const float4* wr4 = (const float4*)W_r;       // 768 float4 each
        const float4* wz4 = (const float4*)W_z;
        const float4* wt4 = (const float4*)W_t;
#pragma unroll
        for (int q = 0; q < 3; ++q) {
            int i = q * 256 + tid;
            wlds[i]        = wr4[i];
            wlds[768 + i]  = wz4[i];
            wlds[1536 + i] = wt4[i];
        }
    }
    __syncthreads();

    // ---- flat-stream the block's CSR row ranges into cat via LDS atomics ----
    {
        const float4* fi4 = (const float4*)fea_in;    // row = 8 float4
        const float4* fo4 = (const float4*)fea_out;
        int r0 = in_off[n0], r1 = in_off[nhi];
        for (int idx = r0 * 8 + tid; idx < r1 * 8; idx += 256) {
            int row = idx >> 3, c4 = idx & 7;
            float4 v = fi4[idx];                      // coalesced stream
            int local = node_in[row] - n0;            // broadcast across 8 lanes
            float* b = &cat[local * CAT_STRIDE + c4 * 4];
            atomicAdd(b + 0, v.x); atomicAdd(b + 1, v.y);
            atomicAdd(b + 2, v.z); atomicAdd(b + 3, v.w);
        }
        int s0 = out_off[n0], s1 = out_off[nhi];
        for (int idx = s0 * 8 + tid; idx < s1 * 8; idx += 256) {
            int row = idx >> 3, c4 = idx & 7;
            float4 v = fo4[idx];
            int local = node_out[row] - n0;
            float* b = &cat[local * CAT_STRIDE + 32 + c4 * 4];
            atomicAdd(b + 0, v.x); atomicAdd(b + 1, v.y);
            atomicAdd(b + 2, v.z); atomicAdd(b + 3, v.w);
        }
    }
    __syncthreads();

    // ---- phase A: r,z (weights from LDS) ----
    float r_[NPT][4], z_[NPT][4];
    {
        float4 br = ((const float4*)b_r)[jq];
        float4 bz = ((const float4*)b_z)[jq];
#pragma unroll
        for (int k = 0; k < NPT; ++k) {
            r_[k][0] = br.x; r_[k][1] = br.y; r_[k][2] = br.z; r_[k][3] = br.w;
            z_[k][0] = bz.x; z_[k][1] = bz.y; z_[k][2] = bz.z; z_[k][3] = bz.w;
        }
    }
#pragma unroll 1
    for (int g = 0; g < 24; ++g) {
        int m0 = g * 4;
        float4 wr[4], wz[4];
#pragma unroll
        for (int i = 0; i < 4; ++i) {
            wr[i] = wlds[(m0 + i) * 8 + jq];
            wz[i] = wlds[768 + (m0 + i) * 8 + jq];
        }
#pragma unroll
        for (int k = 0; k < NPT; ++k) {
            float4 c = cat4[(ng + 32 * k) * 25 + g];
            fma4(r_[k], c.x, wr[0]); fma4(r_[k], c.y, wr[1]);
            fma4(r_[k], c.z, wr[2]); fma4(r_[k], c.w, wr[3]);
            fma4(z_[k], c.x, wz[0]); fma4(z_[k], c.y, wz[1]);
            fma4(z_[k], c.z, wz[2]); fma4(z_[k], c.w, wz[3]);
        }
    }

    float p_[NPT][4];
#pragma unroll
    for (int k = 0; k < NPT; ++k) {
        float4 p = cat4[(ng + 32 * k) * 25 + 16 + jq];
        p_[k][0] = p.x; p_[k][1] = p.y; p_[k][2] = p.z; p_[k][3] = p.w;
#pragma unroll
        for (int j = 0; j < 4; ++j) {
            r_[k][j] = sigm(r_[k][j]) * p_[k][j];     // r := r*p
            z_[k][j] = sigm(z_[k][j]);
        }
    }
    __syncthreads();
#pragma unroll
    for (int k = 0; k < NPT; ++k) {
        float4 rp = {r_[k][0], r_[k][1], r_[k][2], r_[k][3]};
        cat4[(ng + 32 * k) * 25 + 16 + jq] = rp;
    }
    __syncthreads();

    // ---- phase B: t (weights from LDS) ----
    float t_[NPT][4];
    {
        float4 bt = ((const float4*)b_t)[jq];
#pragma unroll
        for (int k = 0; k < NPT; ++k) {
            t_[k][0] = bt.x; t_[k][1] = bt.y; t_[k][2] = bt.z; t_[k][3] = bt.w;
        }
    }
#pragma unroll 1
    for (int g = 0; g < 24; ++g) {
        int m0 = g * 4;
        float4 wt[4];
#pragma unroll
        for (int i = 0; i < 4; ++i)
            wt[i] = wlds[1536 + (m0 + i) * 8 + jq];
#pragma unroll
        for (int k = 0; k < NPT; ++k) {
            float4 c = cat4[(ng + 32 * k) * 25 + g];
            fma4(t_[k], c.x, wt[0]); fma4(t_[k], c.y, wt[1]);
            fma4(t_[k], c.z, wt[2]); fma4(t_[k], c.w, wt[3]);
        }
    }

    // ---- update: prop = p + z*(tanh(t) - p); final step also writes out2 ----
#pragma unroll
    for (int k = 0; k < NPT; ++k) {
        int node = n0 + ng + 32 * k;
        if (node < N_NODES) {
            float4 o;
            o.x = fmaf(z_[k][0], fast_tanh(t_[k][0]) - p_[k][0], p_[k][0]);
            o.y = fmaf(z_[k][1], fast_tanh(t_[k][1]) - p_[k][1], p_[k][1]);
            o.z = fmaf(z_[k][2], fast_tanh(t_[k][2]) - p_[k][2], p_[k][2]);
            o.w = fmaf(z_[k][3], fast_tanh(t_[k][3]) - p_[k][3], p_[k][3]);
            ((float4*)(prop + (size_t)node * DD))[jq] = o;
            if (out2) ((float4*)(out2 + (size_t)node * DD))[jq] = o;
        }
    }
}

extern "C" void kernel_launch(void* const* d_in, const int* in_sizes, int n_in,
                              void* d_out, int out_size, void* d_ws, size_t ws_size,
                              hipStream_t stream) {
    const int*   token  = (const int*)d_in[0];
    const int*   etype  = (const int*)d_in[1];
    const int*   src    = (const int*)d_in[2];
    const int*   dst    = (const int*)d_in[3];
    const float* emb    = (const float*)d_in[4];
    const float* W_edge = (const float*)d_in[5];
    const float* W_r    = (const float*)d_in[6];
    const float* b_r    = (const float*)d_in[7];
    const float* W_z    = (const float*)d_in[8];
    const float* b_z    = (const float*)d_in[9];
    const float* W_t    = (const float*)d_in[10];
    const float* b_t    = (const float*)d_in[11];
    float* out = (float*)d_out;

    // Persistent workspace (~34.5 MB; ws_size = 256 MB per the poison fill):
    float* prop    = (float*)d_ws;                            // N*D
    float* fea_in  = prop    + (size_t)N_NODES * DD;          // (E+1)*D
    float* fea_out = fea_in  + (size_t)(N_EDGES + 1) * DD;    // (E+1)*D
    int* in_off   = (int*)(fea_out + (size_t)(N_EDGES + 1) * DD); // N+1
    int* out_off  = in_off + (N_NODES + 1);                   // N+1
    int* se       = out_off + (N_NODES + 1);                  // CAP
    int* spi      = se + CAP;                                 // CAP
    int* spo      = spi + CAP;                                // CAP
    int* node_in  = spo + CAP;                                // E
    int* node_out = node_in + N_EDGES;                        // E

    // Setup temporaries OVERLAID on fea_in (dead before first edge_kernel
    // write; step loop never reads them).
    int* cnt      = (int*)fea_in;                             // 2N+8
    int* cnt_in   = cnt;
    int* cnt_out  = cnt + N_NODES;
    int* tcnt     = cnt + 2 * N_NODES;
    int* rank_in  = cnt + 2 * N_NODES + ETYPES;               // E
    int* rank_out = rank_in + N_EDGES;                        // E
    int* qe       = rank_out + N_EDGES;                       // E
    int* bsum     = qe + N_EDGES;                             // 2*SCAN_B
    int* ebase    = bsum + 2 * SCAN_B;                        // 2*SCAN_B

    // per-launch setup: prop init + type-bucketed CSR build
    init_kernel<<<(N_NODES * DD) / 256, 256, 0, stream>>>(token, emb, prop, cnt,
                                                          se, spi, spo);
    hist_kernel<<<(N_EDGES + 255) / 256, 256, 0, stream>>>(
        etype, src, dst, cnt_in, cnt_out, tcnt, rank_in, rank_out, qe);
    scan1<<<2 * SCAN_B, 1024, 0, stream>>>(cnt_in, cnt_out, in_off, out_off, bsum);
    scan2<<<1, 128, 0, stream>>>(bsum, ebase, in_off, out_off);
    scan3<<<2 * SCAN_B, 1024, 0, stream>>>(in_off, out_off, ebase);
    place_kernel<<<(N_EDGES + 255) / 256, 256, 0, stream>>>(
        src, dst, in_off, out_off, rank_in, rank_out, qe, se, spi, spo,
        node_in, node_out);

    for (int step = 0; step < STEPS; ++step) {
        edge_kernel<<<CAP / 64, 256, 0, stream>>>(se, spi, spo, W_edge, prop,
                                                  fea_in, fea_out);
        gru_kernel<<<(N_NODES + NPB - 1) / NPB, 256, 0, stream>>>(
            W_r, b_r, W_z, b_z, W_t, b_t, fea_in, fea_out, in_off, out_off,
            node_in, node_out, prop, (step == STEPS - 1) ? out : nullptr);
    }
}